// Round 1
// baseline (2727.704 us; speedup 1.0000x reference)
//
#include <hip/hip_runtime.h>

#define H    128
#define TILE 16

__global__ __launch_bounds__(256) void edgedec_f32(
    const float* __restrict__ z_user,
    const float* __restrict__ z_rest,
    const int*   __restrict__ row,
    const int*   __restrict__ col,
    const float* __restrict__ W1,
    const float* __restrict__ b1,
    const float* __restrict__ W2,
    const float* __restrict__ b2,
    const float* __restrict__ W3,
    const float* __restrict__ b3,
    float* __restrict__ out,
    int nEdge)
{
    __shared__ float zt[TILE][2 * H];   // 16 KB: gathered concat embeddings
    __shared__ float h1t[TILE][H];      // 8 KB: h1 transposed; reused as w3*h2 scratch
    __shared__ float part[TILE][16];    // 1 KB: reduction partials

    const int tid  = threadIdx.x;
    const int base = blockIdx.x * TILE;

    // ---- gather: 4 edges per iteration, 64 threads per edge (32 user + 32 rest) ----
    {
        const int e0   = tid >> 6;        // 0..3 (wave-uniform)
        const int half = (tid >> 5) & 1;  // 0: user half, 1: rest half
        const int q    = tid & 31;        // float4 slot within the 128-float row
        #pragma unroll
        for (int it = 0; it < TILE / 4; ++it) {
            const int e  = e0 + it * 4;
            const int ge = base + e;
            if (ge < nEdge) {
                const float* src = half ? (z_rest + (size_t)col[ge] * H)
                                        : (z_user + (size_t)row[ge] * H);
                const float4 v = *(const float4*)(src + q * 4);
                *(float4*)&zt[e][half * H + q * 4] = v;
            }
        }
    }
    __syncthreads();

    const int j = tid & (H - 1);   // hidden unit 0..127
    const int g = tid >> 7;        // edge-group: 0 -> edges 0..7, 1 -> edges 8..15
    float acc[8];

    // ---- layer 1: h1[j][e] = relu(b1[j] + sum_k W1[j][k] * z[e][k]), k in [0,256) ----
    {
        const float bj = b1[j];
        #pragma unroll
        for (int e = 0; e < 8; ++e) acc[e] = bj;
        const float4* wp = (const float4*)(W1 + (size_t)j * (2 * H));
        for (int k4 = 0; k4 < (2 * H) / 4; ++k4) {
            const float4 w = wp[k4];
            #pragma unroll
            for (int e = 0; e < 8; ++e) {
                // wave-uniform address -> LDS broadcast read, no bank conflicts
                const float4 z = *(const float4*)&zt[g * 8 + e][k4 * 4];
                acc[e] = fmaf(w.x, z.x, acc[e]);
                acc[e] = fmaf(w.y, z.y, acc[e]);
                acc[e] = fmaf(w.z, z.z, acc[e]);
                acc[e] = fmaf(w.w, z.w, acc[e]);
            }
        }
        #pragma unroll
        for (int e = 0; e < 8; ++e) h1t[g * 8 + e][j] = fmaxf(acc[e], 0.0f);
    }
    __syncthreads();

    // ---- layer 2: h2[j][e] = relu(b2[j] + sum_k W2[j][k] * h1[k][e]), k in [0,128) ----
    {
        const float bj = b2[j];
        #pragma unroll
        for (int e = 0; e < 8; ++e) acc[e] = bj;
        const float4* wp = (const float4*)(W2 + (size_t)j * H);
        for (int k4 = 0; k4 < H / 4; ++k4) {
            const float4 w = wp[k4];
            #pragma unroll
            for (int e = 0; e < 8; ++e) {
                const float4 h = *(const float4*)&h1t[g * 8 + e][k4 * 4];
                acc[e] = fmaf(w.x, h.x, acc[e]);
                acc[e] = fmaf(w.y, h.y, acc[e]);
                acc[e] = fmaf(w.z, h.z, acc[e]);
                acc[e] = fmaf(w.w, h.w, acc[e]);
            }
        }
        const float w3j = W3[j];
        __syncthreads();  // everyone done reading h1t before we overwrite it
        #pragma unroll
        for (int e = 0; e < 8; ++e) h1t[g * 8 + e][j] = w3j * fmaxf(acc[e], 0.0f);
    }
    __syncthreads();

    // ---- layer 3 reduce: out[e] = b3 + sum_j h1t[e][j]  (two-stage) ----
    {
        const int e = tid >> 4;   // 0..15
        const int p = tid & 15;   // 0..15
        float s = 0.0f;
        #pragma unroll
        for (int i = 0; i < 8; ++i) s += h1t[e][p * 8 + i];
        part[e][p] = s;
    }
    __syncthreads();
    if (tid < TILE) {
        const int ge = base + tid;
        if (ge < nEdge) {
            float s = b3[0];
            #pragma unroll
            for (int i = 0; i < 16; ++i) s += part[tid][i];
            out[ge] = s;
        }
    }
}

extern "C" void kernel_launch(void* const* d_in, const int* in_sizes, int n_in,
                              void* d_out, int out_size, void* d_ws, size_t ws_size,
                              hipStream_t stream) {
    const float* z_user = (const float*)d_in[0];
    const float* z_rest = (const float*)d_in[1];
    const int*   row    = (const int*)d_in[2];
    const int*   col    = (const int*)d_in[3];
    const float* W1     = (const float*)d_in[4];
    const float* b1     = (const float*)d_in[5];
    const float* W2     = (const float*)d_in[6];
    const float* b2     = (const float*)d_in[7];
    const float* W3     = (const float*)d_in[8];
    const float* b3     = (const float*)d_in[9];
    float* out = (float*)d_out;

    const int nEdge   = in_sizes[2];
    const int nBlocks = (nEdge + TILE - 1) / TILE;
    hipLaunchKernelGGL(edgedec_f32, dim3(nBlocks), dim3(256), 0, stream,
                       z_user, z_rest, row, col, W1, b1, W2, b2, W3, b3, out, nEdge);
}

// Round 3
// 181.713 us; speedup vs baseline: 15.0111x; 15.0111x over previous
//
#include <hip/hip_runtime.h>

typedef _Float16 f16;
typedef _Float16 f16x8 __attribute__((ext_vector_type(8)));
typedef float    f32x4 __attribute__((ext_vector_type(4)));

#define H 128

// ============================================================================
// Kernel A: precompute U = zu@W1u^T + b1  (f16), R = zr@W1r^T (f16),
//           and convert W2 -> f16.
// One block = 64 output rows, 4 waves x 16 rows, MFMA 16x16x32 f16.
// A/B fragments both use k = 8*(lane>>4)+i  (k-permutation-invariant vs HW map).
// ============================================================================
__global__ __launch_bounds__(256) void precompute_kernel(
    const float* __restrict__ zu, const float* __restrict__ zr,
    const float* __restrict__ W1, const float* __restrict__ b1,
    const float* __restrict__ W2,
    f16* __restrict__ U, f16* __restrict__ R, f16* __restrict__ W2h,
    int nU, int nR, int nUblk, int nRblk)
{
    const int bid = blockIdx.x;
    if (bid >= nUblk + nRblk) {
        // single block: convert W2 (128x128) to f16
        const int t = threadIdx.x;
        #pragma unroll
        for (int i = 0; i < 64; i += 4) {
            const int idx = t * 64 + i;
            const float4 v = *(const float4*)(W2 + idx);
            W2h[idx + 0] = (f16)v.x;
            W2h[idx + 1] = (f16)v.y;
            W2h[idx + 2] = (f16)v.z;
            W2h[idx + 3] = (f16)v.w;
        }
        return;
    }

    const bool  isU   = bid < nUblk;
    const float* src  = isU ? zu : zr;
    f16*        dst   = isU ? U : R;
    const int   nrows = isU ? nU : nR;
    const int   base  = (isU ? bid : bid - nUblk) * 64;
    const int   kofs  = isU ? 0 : H;   // W1 column offset (user half vs rest half)

    const int tid  = threadIdx.x;
    const int wid  = tid >> 6;
    const int lane = tid & 63;
    const int lg   = lane >> 4;   // lane-group 0..3
    const int lr   = lane & 15;   // 0..15

    // ---- A fragments: 16 rows of src per wave, f32 -> f16 ----
    const int arow   = base + wid * 16 + lr;
    const int arow_c = arow < nrows ? arow : (nrows - 1);
    f16x8 afr[4];
    #pragma unroll
    for (int kt = 0; kt < 4; ++kt) {
        const float* p = src + (size_t)arow_c * H + kt * 32 + lg * 8;
        const float4 x0 = *(const float4*)p;
        const float4 x1 = *(const float4*)(p + 4);
        afr[kt] = (f16x8){(f16)x0.x, (f16)x0.y, (f16)x0.z, (f16)x0.w,
                          (f16)x1.x, (f16)x1.y, (f16)x1.z, (f16)x1.w};
    }

    // ---- accumulators, bias folded for U ----
    f32x4 acc[8];
    #pragma unroll
    for (int nt = 0; nt < 8; ++nt) {
        const float b = isU ? b1[lr + 16 * nt] : 0.0f;
        acc[nt] = (f32x4){b, b, b, b};
    }

    // ---- MFMA: B frags streamed from W1 (L2-hot), converted on the fly ----
    #pragma unroll
    for (int kt = 0; kt < 4; ++kt) {
        #pragma unroll
        for (int nt = 0; nt < 8; ++nt) {
            const float* p = W1 + (size_t)(lr + 16 * nt) * (2 * H) + kofs + kt * 32 + lg * 8;
            const float4 w0 = *(const float4*)p;
            const float4 w1 = *(const float4*)(p + 4);
            const f16x8 bfr = (f16x8){(f16)w0.x, (f16)w0.y, (f16)w0.z, (f16)w0.w,
                                      (f16)w1.x, (f16)w1.y, (f16)w1.z, (f16)w1.w};
            acc[nt] = __builtin_amdgcn_mfma_f32_16x16x32_f16(afr[kt], bfr, acc[nt], 0, 0, 0);
        }
    }

    // ---- repack via LDS, coalesced f16 store ----
    __shared__ f16 lds[64][136];
    #pragma unroll
    for (int nt = 0; nt < 8; ++nt)
        #pragma unroll
        for (int r = 0; r < 4; ++r)
            lds[wid * 16 + lg * 4 + r][lr + 16 * nt] = (f16)acc[nt][r];
    __syncthreads();

    // each thread owns 32 f16 = 64 B = 4 x uint4  (round-2 bug: copied only 2)
    const int srow = tid >> 2, q = tid & 3;
    const int grow = base + srow;
    if (grow < nrows) {
        const uint4* s = (const uint4*)&lds[srow][q * 32];
        uint4* d = (uint4*)(dst + (size_t)grow * H + q * 32);
        d[0] = s[0];
        d[1] = s[1];
        d[2] = s[2];
        d[3] = s[3];
    }
}

// ============================================================================
// Kernel B: per edge  out = W3·relu(W2·relu(U[row]+R[col]) + b2) + b3
// 64 edges/block (4 waves x 16), gather straight into A-fragments (no LDS),
// W2 fragments resident in VGPRs, grid-stride with 1-tile software prefetch.
// ============================================================================
__global__ __launch_bounds__(256, 2) void edge_kernel(
    const int* __restrict__ row, const int* __restrict__ col,
    const f16* __restrict__ U, const f16* __restrict__ R,
    const f16* __restrict__ W2h, const float* __restrict__ b2,
    const float* __restrict__ W3, const float* __restrict__ b3,
    float* __restrict__ out, int nEdge, int nTiles)
{
    const int tid  = threadIdx.x;
    const int wid  = tid >> 6;
    const int lane = tid & 63;
    const int lg   = lane >> 4;
    const int lr   = lane & 15;

    // ---- resident W2 fragments: B[k][n] = W2[n][k], k-map 8*lg+i (+32*kt) ----
    f16x8 w2f[4][8];
    #pragma unroll
    for (int kt = 0; kt < 4; ++kt)
        #pragma unroll
        for (int nt = 0; nt < 8; ++nt)
            w2f[kt][nt] = *(const f16x8*)(W2h + (size_t)(lr + 16 * nt) * H + kt * 32 + lg * 8);

    float b2v[8], w3v[8];
    #pragma unroll
    for (int nt = 0; nt < 8; ++nt) {
        b2v[nt] = b2[lr + 16 * nt];
        w3v[nt] = W3[lr + 16 * nt];
    }
    const float b3s = b3[0];

    const int stride = gridDim.x;
    int t = blockIdx.x;
    if (t >= nTiles) return;

    // ---- prologue: gather tile t, prefetch indices for t+stride ----
    int e  = t * 64 + wid * 16 + lr;
    int ec = e < nEdge ? e : (nEdge - 1);
    int ri = row[ec], ci = col[ec];
    f16x8 fr[4];
    #pragma unroll
    for (int kt = 0; kt < 4; ++kt) {
        const f16x8 u = *(const f16x8*)(U + (size_t)ri * H + kt * 32 + lg * 8);
        const f16x8 r = *(const f16x8*)(R + (size_t)ci * H + kt * 32 + lg * 8);
        f16x8 s = u + r;
        #pragma unroll
        for (int i = 0; i < 8; ++i) s[i] = s[i] > (f16)0 ? s[i] : (f16)0;
        fr[kt] = s;
    }
    int riN = 0, ciN = 0;
    {
        const int tn = t + stride;
        if (tn < nTiles) {
            int en = tn * 64 + wid * 16 + lr;
            en = en < nEdge ? en : (nEdge - 1);
            riN = row[en];
            ciN = col[en];
        }
    }

    while (true) {
        const int  tnext = t + stride;
        const bool more  = tnext < nTiles;

        // prefetch gathers for next tile (indices already resident)
        f16x8 gu[4], gr[4];
        if (more) {
            #pragma unroll
            for (int kt = 0; kt < 4; ++kt) {
                gu[kt] = *(const f16x8*)(U + (size_t)riN * H + kt * 32 + lg * 8);
                gr[kt] = *(const f16x8*)(R + (size_t)ciN * H + kt * 32 + lg * 8);
            }
        }
        // prefetch indices two tiles ahead
        int riN2 = 0, ciN2 = 0;
        const int tnn = tnext + stride;
        if (more && tnn < nTiles) {
            int en2 = tnn * 64 + wid * 16 + lr;
            en2 = en2 < nEdge ? en2 : (nEdge - 1);
            riN2 = row[en2];
            ciN2 = col[en2];
        }

        // ---- layer 2 MFMA ----
        f32x4 acc[8];
        #pragma unroll
        for (int nt = 0; nt < 8; ++nt) acc[nt] = (f32x4){b2v[nt], b2v[nt], b2v[nt], b2v[nt]};
        #pragma unroll
        for (int kt = 0; kt < 4; ++kt)
            #pragma unroll
            for (int nt = 0; nt < 8; ++nt)
                acc[nt] = __builtin_amdgcn_mfma_f32_16x16x32_f16(fr[kt], w2f[kt][nt], acc[nt], 0, 0, 0);

        // ---- epilogue: relu -> *w3 -> reduce across 16 cols -> store ----
        float s0 = 0.f, s1 = 0.f, s2 = 0.f, s3 = 0.f;
        #pragma unroll
        for (int nt = 0; nt < 8; ++nt) {
            const f32x4 a = acc[nt];
            s0 += fmaxf(a[0], 0.f) * w3v[nt];
            s1 += fmaxf(a[1], 0.f) * w3v[nt];
            s2 += fmaxf(a[2], 0.f) * w3v[nt];
            s3 += fmaxf(a[3], 0.f) * w3v[nt];
        }
        #pragma unroll
        for (int m = 1; m < 16; m <<= 1) {
            s0 += __shfl_xor(s0, m);
            s1 += __shfl_xor(s1, m);
            s2 += __shfl_xor(s2, m);
            s3 += __shfl_xor(s3, m);
        }
        if (lr == 0) {
            const int ebase = t * 64 + wid * 16 + lg * 4;
            if (ebase + 0 < nEdge) out[ebase + 0] = s0 + b3s;
            if (ebase + 1 < nEdge) out[ebase + 1] = s1 + b3s;
            if (ebase + 2 < nEdge) out[ebase + 2] = s2 + b3s;
            if (ebase + 3 < nEdge) out[ebase + 3] = s3 + b3s;
        }

        if (!more) break;
        #pragma unroll
        for (int kt = 0; kt < 4; ++kt) {
            f16x8 s = gu[kt] + gr[kt];
            #pragma unroll
            for (int i = 0; i < 8; ++i) s[i] = s[i] > (f16)0 ? s[i] : (f16)0;
            fr[kt] = s;
        }
        riN = riN2;
        ciN = ciN2;
        t = tnext;
    }
}

// ============================================================================
// Fallback: round-1 fp32 kernel (used only if ws_size is too small)
// ============================================================================
#define TILE 16
__global__ __launch_bounds__(256) void edgedec_f32(
    const float* __restrict__ z_user, const float* __restrict__ z_rest,
    const int* __restrict__ row, const int* __restrict__ col,
    const float* __restrict__ W1, const float* __restrict__ b1,
    const float* __restrict__ W2, const float* __restrict__ b2,
    const float* __restrict__ W3, const float* __restrict__ b3,
    float* __restrict__ out, int nEdge)
{
    __shared__ float zt[TILE][2 * H];
    __shared__ float h1t[TILE][H];
    __shared__ float part[TILE][16];
    const int tid  = threadIdx.x;
    const int base = blockIdx.x * TILE;
    {
        const int e0 = tid >> 6, half = (tid >> 5) & 1, q = tid & 31;
        #pragma unroll
        for (int it = 0; it < TILE / 4; ++it) {
            const int e = e0 + it * 4, ge = base + e;
            if (ge < nEdge) {
                const float* src = half ? (z_rest + (size_t)col[ge] * H)
                                        : (z_user + (size_t)row[ge] * H);
                *(float4*)&zt[e][half * H + q * 4] = *(const float4*)(src + q * 4);
            }
        }
    }
    __syncthreads();
    const int j = tid & (H - 1), g = tid >> 7;
    float acc[8];
    {
        const float bj = b1[j];
        #pragma unroll
        for (int e = 0; e < 8; ++e) acc[e] = bj;
        const float4* wp = (const float4*)(W1 + (size_t)j * (2 * H));
        for (int k4 = 0; k4 < (2 * H) / 4; ++k4) {
            const float4 w = wp[k4];
            #pragma unroll
            for (int e = 0; e < 8; ++e) {
                const float4 z = *(const float4*)&zt[g * 8 + e][k4 * 4];
                acc[e] = fmaf(w.x, z.x, acc[e]); acc[e] = fmaf(w.y, z.y, acc[e]);
                acc[e] = fmaf(w.z, z.z, acc[e]); acc[e] = fmaf(w.w, z.w, acc[e]);
            }
        }
        #pragma unroll
        for (int e = 0; e < 8; ++e) h1t[g * 8 + e][j] = fmaxf(acc[e], 0.0f);
    }
    __syncthreads();
    {
        const float bj = b2[j];
        #pragma unroll
        for (int e = 0; e < 8; ++e) acc[e] = bj;
        const float4* wp = (const float4*)(W2 + (size_t)j * H);
        for (int k4 = 0; k4 < H / 4; ++k4) {
            const float4 w = wp[k4];
            #pragma unroll
            for (int e = 0; e < 8; ++e) {
                const float4 h = *(const float4*)&h1t[g * 8 + e][k4 * 4];
                acc[e] = fmaf(w.x, h.x, acc[e]); acc[e] = fmaf(w.y, h.y, acc[e]);
                acc[e] = fmaf(w.z, h.z, acc[e]); acc[e] = fmaf(w.w, h.w, acc[e]);
            }
        }
        const float w3j = W3[j];
        __syncthreads();
        #pragma unroll
        for (int e = 0; e < 8; ++e) h1t[g * 8 + e][j] = w3j * fmaxf(acc[e], 0.0f);
    }
    __syncthreads();
    {
        const int e = tid >> 4, p = tid & 15;
        float s = 0.0f;
        #pragma unroll
        for (int i = 0; i < 8; ++i) s += h1t[e][p * 8 + i];
        part[e][p] = s;
    }
    __syncthreads();
    if (tid < TILE) {
        const int ge = base + tid;
        if (ge < nEdge) {
            float s = b3[0];
            #pragma unroll
            for (int i = 0; i < 16; ++i) s += part[tid][i];
            out[ge] = s;
        }
    }
}

extern "C" void kernel_launch(void* const* d_in, const int* in_sizes, int n_in,
                              void* d_out, int out_size, void* d_ws, size_t ws_size,
                              hipStream_t stream) {
    const float* z_user = (const float*)d_in[0];
    const float* z_rest = (const float*)d_in[1];
    const int*   row    = (const int*)d_in[2];
    const int*   col    = (const int*)d_in[3];
    const float* W1     = (const float*)d_in[4];
    const float* b1     = (const float*)d_in[5];
    const float* W2     = (const float*)d_in[6];
    const float* b2     = (const float*)d_in[7];
    const float* W3     = (const float*)d_in[8];
    const float* b3     = (const float*)d_in[9];
    float* out = (float*)d_out;

    const int nU    = in_sizes[0] / H;
    const int nR    = in_sizes[1] / H;
    const int nEdge = in_sizes[2];

    const size_t uBytes  = (size_t)nU * H * sizeof(f16);
    const size_t rBytes  = (size_t)nR * H * sizeof(f16);
    const size_t w2Bytes = (size_t)H * H * sizeof(f16);
    const size_t need    = uBytes + rBytes + w2Bytes;

    if (ws_size < need) {
        // fallback: fp32 reference-style kernel
        const int nBlocks = (nEdge + TILE - 1) / TILE;
        hipLaunchKernelGGL(edgedec_f32, dim3(nBlocks), dim3(256), 0, stream,
                           z_user, z_rest, row, col, W1, b1, W2, b2, W3, b3, out, nEdge);
        return;
    }

    f16* U   = (f16*)d_ws;
    f16* R   = (f16*)((char*)d_ws + uBytes);
    f16* W2h = (f16*)((char*)d_ws + uBytes + rBytes);

    const int nUblk = (nU + 63) / 64;
    const int nRblk = (nR + 63) / 64;
    hipLaunchKernelGGL(precompute_kernel, dim3(nUblk + nRblk + 1), dim3(256), 0, stream,
                       z_user, z_rest, W1, b1, W2, U, R, W2h, nU, nR, nUblk, nRblk);

    const int nTiles = (nEdge + 63) / 64;
    const int grid   = nTiles < 1024 ? nTiles : 1024;
    hipLaunchKernelGGL(edge_kernel, dim3(grid), dim3(256), 0, stream,
                       row, col, U, R, W2h, b2, W3, b3, out, nEdge, nTiles);
}